// Round 8
// baseline (71.798 us; speedup 1.0000x reference)
//
#include <hip/hip_runtime.h>

typedef __attribute__((ext_vector_type(2))) float f32x2;
typedef __attribute__((ext_vector_type(4))) float f32x4;
typedef __attribute__((ext_vector_type(4))) float float4v;
typedef __attribute__((ext_vector_type(8))) short bf16x8;
typedef __attribute__((ext_vector_type(8))) unsigned short ushort8;

#define DEVI static __device__ __forceinline__

namespace {
constexpr int kL = 2048, kS = 2048, kH = 8;
constexpr int QB = 64, KVB = 64, NKT = kS / KVB;
constexpr float kC = 0.18033688f;        // (1/8) * log2(e), folded into Q
constexpr int TILE = 8192;               // bytes per K or V tile
constexpr int BH = 32 * TILE;            // bytes per (b,h) per tensor
constexpr int LBUF = 2 * TILE;           // 16384 B per LDS buffer (K|V)
}

// XOR swizzle on flat byte offset for [rows][64] bf16 tiles (128B row stride).
DEVI int swz(int byteoff) { return byteoff ^ (((byteoff >> 7) & 7) << 4); }

DEVI unsigned cvtpk(float lo, float hi) {
  unsigned r;
  asm("v_cvt_pk_bf16_f32 %0, %1, %2" : "=v"(r) : "v"(lo), "v"(hi));
  return r;
}

DEVI f32x2 pkmul(f32x2 a, f32x2 b) {
  f32x2 r;
  asm("v_pk_mul_f32 %0, %1, %2" : "=v"(r) : "v"(a), "v"(b));
  return r;
}

// ---------- prepass 1: K -> tiled, PRE-SWIZZLED bf16 tiles; kn2 separate ----------
__global__ __launch_bounds__(256) void prep_k(const float* __restrict__ Kg,
                                              char* __restrict__ Kb,
                                              float* __restrict__ kn2g) {
  const int chunk = (int)blockIdx.x * 256 + (int)threadIdx.x;  // one 16B chunk
  const int tile = chunk >> 9;
  const int i = chunk & 511;
  const int bh = tile >> 5, kt = tile & 31;
  const int b = bh >> 3, h = bh & 7;
  const int row = i >> 3;
  const int colsel = (i & 7) ^ (row & 7);     // swz on chunk index
  const int s = kt * 64 + row;
  const float* src = Kg + (((size_t)b * kS + s) * kH + h) * 64 + colsel * 8;
  float4v v0 = *(const float4v*)(src);
  float4v v1 = *(const float4v*)(src + 4);
  float pn = v0.x*v0.x + v0.y*v0.y + v0.z*v0.z + v0.w*v0.w
           + v1.x*v1.x + v1.y*v1.y + v1.z*v1.z + v1.w*v1.w;
  union { unsigned w[4]; ushort8 u; } o;
  o.w[0] = cvtpk(v0.x, v0.y); o.w[1] = cvtpk(v0.z, v0.w);
  o.w[2] = cvtpk(v1.x, v1.y); o.w[3] = cvtpk(v1.z, v1.w);
  *(ushort8*)(Kb + (size_t)tile * TILE + i * 16) = o.u;
  pn += __shfl_xor(pn, 1);
  pn += __shfl_xor(pn, 2);
  pn += __shfl_xor(pn, 4);
  if ((i & 7) == 0) kn2g[tile * 64 + row] = pn;  // exact f32 |k|^2
}

// ---------- prepass 2: V -> tiled, sigma-permuted, PRE-SWIZZLED bf16 ----------
__global__ __launch_bounds__(256) void prep_v(const float* __restrict__ Vg,
                                              char* __restrict__ Vt) {
  __shared__ char tile[64 * 128];  // [s][d] bf16, swizzled
  const int t = (int)threadIdx.x;
  const int bid = (int)blockIdx.x;
  const int st = bid & 31, bh = bid >> 5;
  const int b = bh >> 3, h = bh & 7;
  {
    const int sl = t >> 2, c0 = (t & 3) * 16;
    const float* src = Vg + (((size_t)b * kS + st * 64 + sl) * kH + h) * 64 + c0;
    float4v v0 = *(const float4v*)(src);
    float4v v1 = *(const float4v*)(src + 4);
    float4v v2 = *(const float4v*)(src + 8);
    float4v v3 = *(const float4v*)(src + 12);
    union { unsigned w[4]; ushort8 u; } t0, t1;
    t0.w[0] = cvtpk(v0.x, v0.y); t0.w[1] = cvtpk(v0.z, v0.w);
    t0.w[2] = cvtpk(v1.x, v1.y); t0.w[3] = cvtpk(v1.z, v1.w);
    t1.w[0] = cvtpk(v2.x, v2.y); t1.w[1] = cvtpk(v2.z, v2.w);
    t1.w[2] = cvtpk(v3.x, v3.y); t1.w[3] = cvtpk(v3.z, v3.w);
    *(ushort8*)(tile + swz(sl * 128 + c0 * 2)) = t0.u;
    *(ushort8*)(tile + swz(sl * 128 + c0 * 2 + 16)) = t1.u;
  }
  __syncthreads();
  char* dst = Vt + (size_t)bid * TILE;
#pragma unroll
  for (int cc = 0; cc < 2; ++cc) {
    const int i = t * 2 + cc;
    const int z = swz(i * 16);
    const int d = z >> 7;
    const int k0 = ((z >> 4) & 7) * 8;
    union { unsigned short s[8]; ushort8 u; } o;
#pragma unroll
    for (int j = 0; j < 8; ++j) {
      const int k = k0 + j;
      const int sig = (((k >> 5) * 2 + ((k & 7) >> 2)) << 4) |
                      (((k >> 3) & 3) << 2) | (k & 3);
      o.s[j] = *(const unsigned short*)(tile + swz(sig * 128 + d * 2));
    }
    *(ushort8*)(dst + i * 16) = o.u;
  }
}

// ---------- main attention kernel ----------
__global__ __launch_bounds__(256, 4) void geo_attn_kernel(
    const float* __restrict__ Qg, const char* __restrict__ Kb,
    const char* __restrict__ Vt, const float* __restrict__ kn2g,
    float* __restrict__ Og) {
  // two buffers, each: 8192 B K tile | 8192 B V tile (exactly 32 KiB total)
  __shared__ char lds[2 * LBUF];

  const int t = (int)threadIdx.x;
  const int wv = t >> 6, lane = t & 63, gg = lane >> 4, cl = lane & 15;
  // XCD-aware decode: blocks n with n&7==c land on XCD c (dispatch round-robin);
  // give each XCD 4 bh values so K/V tiles stay in its private L2.
  const int n = (int)blockIdx.x;
  const int bh = (n & 7) * 4 + ((n >> 3) & 3);
  const int l0 = (n >> 5) * QB;
  const int b = bh >> 3, h = bh & 7;

  // ---- Q fragment straight from global, scaled by kC; exact f32 |q|^2 ----
  const int q = l0 + wv * 16 + cl;
  const float* qp = Qg + (((size_t)b * kL + q) * kH + h) * 64;
  float4v x0 = *(const float4v*)(qp + gg * 8);
  float4v x1 = *(const float4v*)(qp + gg * 8 + 4);
  float4v x2 = *(const float4v*)(qp + gg * 8 + 32);
  float4v x3 = *(const float4v*)(qp + gg * 8 + 36);
  x0 *= kC; x1 *= kC; x2 *= kC; x3 *= kC;
  float pn = 0.f;
#pragma unroll
  for (int j = 0; j < 4; ++j) {
    pn = fmaf(x0[j], x0[j], pn); pn = fmaf(x1[j], x1[j], pn);
    pn = fmaf(x2[j], x2[j], pn); pn = fmaf(x3[j], x3[j], pn);
  }
  union frag { bf16x8 v; unsigned w[4]; };
  frag qb0, qb1;
  qb0.w[0] = cvtpk(x0.x, x0.y); qb0.w[1] = cvtpk(x0.z, x0.w);
  qb0.w[2] = cvtpk(x1.x, x1.y); qb0.w[3] = cvtpk(x1.z, x1.w);
  qb1.w[0] = cvtpk(x2.x, x2.y); qb1.w[1] = cvtpk(x2.z, x2.w);
  qb1.w[2] = cvtpk(x3.x, x3.y); qb1.w[3] = cvtpk(x3.z, x3.w);
  pn += __shfl_xor(pn, 16);
  pn += __shfl_xor(pn, 32);
  const f32x2 qn2d = {pn, pn};  // kC^2 * |q|^2 (full row), duplicated

  frag vone;  // all-ones bf16 B-fragment for P row-sums on the MFMA pipe
  vone.w[0] = vone.w[1] = vone.w[2] = vone.w[3] = 0x3F803F80u;

  // ---- per-lane LDS read bases; all reads are base + compile-time offset ----
  const char* pA = lds + ((cl * 128 + gg * 16) ^ ((cl & 7) << 4));
  const char* pB = lds + ((cl * 128 + gg * 16 + 64) ^ ((cl & 7) << 4));

  // ---- staging: waves 0-1 own the K tile (4KB each), waves 2-3 the V tile ----
  const bool isK = (wv < 2);
  const char* gp = (isK ? Kb : Vt) + (size_t)bh * BH + (wv & 1) * 4096 + lane * 16;
  const int ldsoff = (isK ? 0 : TILE) + (wv & 1) * 4096;
  char* const sd0 = lds + ldsoff;          // stage dest, buffer 0
  char* const sd1 = lds + LBUF + ldsoff;   // stage dest, buffer 1
  const float* kn2p = kn2g + bh * 2048 + gg * 4;

#define STAGE(SD) do { \
    __builtin_amdgcn_global_load_lds((__attribute__((address_space(1))) void*)(gp),        (__attribute__((address_space(3))) void*)(SD),        16, 0, 0); \
    __builtin_amdgcn_global_load_lds((__attribute__((address_space(1))) void*)(gp + 1024), (__attribute__((address_space(3))) void*)((SD) + 1024), 16, 0, 0); \
    __builtin_amdgcn_global_load_lds((__attribute__((address_space(1))) void*)(gp + 2048), (__attribute__((address_space(3))) void*)((SD) + 2048), 16, 0, 0); \
    __builtin_amdgcn_global_load_lds((__attribute__((address_space(1))) void*)(gp + 3072), (__attribute__((address_space(3))) void*)((SD) + 3072), 16, 0, 0); \
    gp += TILE; \
  } while (0)

  f32x4 oacc[4];
#pragma unroll
  for (int dt = 0; dt < 4; ++dt) oacc[dt] = (f32x4){0.f, 0.f, 0.f, 0.f};
  f32x4 lacc = (f32x4){0.f, 0.f, 0.f, 0.f};

  // One tile body; BO = buffer byte-offset (0 or LBUF), KF = kn2 float offset.
#define BODY(BO, KF) do { \
    float4v kn2v[4]; \
    _Pragma("unroll") for (int nt = 0; nt < 4; ++nt) \
      kn2v[nt] = *(const float4v*)(kn2p + (KF) + nt * 16); \
    f32x4 dacc[4]; \
    __builtin_amdgcn_s_setprio(1); \
    _Pragma("unroll") for (int nt = 0; nt < 4; ++nt) { \
      bf16x8 ka0 = *(const bf16x8*)(pA + (BO) + nt * 2048); \
      bf16x8 ka1 = *(const bf16x8*)(pB + (BO) + nt * 2048); \
      f32x4 acc = {0.f, 0.f, 0.f, 0.f}; \
      acc = __builtin_amdgcn_mfma_f32_16x16x32_bf16(ka0, qb0.v, acc, 0, 0, 0); \
      acc = __builtin_amdgcn_mfma_f32_16x16x32_bf16(ka1, qb1.v, acc, 0, 0, 0); \
      dacc[nt] = acc; } \
    __builtin_amdgcn_s_setprio(0); \
    f32x2 qk2lo[4], qk2hi[4]; \
    _Pragma("unroll") for (int nt = 0; nt < 4; ++nt) { \
      const f32x2 klo = {kn2v[nt][0], kn2v[nt][1]}; \
      const f32x2 khi = {kn2v[nt][2], kn2v[nt][3]}; \
      qk2lo[nt] = pkmul(qn2d, klo); \
      qk2hi[nt] = pkmul(qn2d, khi); } \
    bf16x8 vb0[4], vb1[4]; \
    _Pragma("unroll") for (int dt = 0; dt < 4; ++dt) { \
      vb0[dt] = *(const bf16x8*)(pA + (BO) + TILE + dt * 2048); \
      vb1[dt] = *(const bf16x8*)(pB + (BO) + TILE + dt * 2048); } \
    float sc[4][4]; \
    _Pragma("unroll") for (int nt = 0; nt < 2; ++nt) \
      _Pragma("unroll") for (int r = 0; r < 4; ++r) { \
        const float d = dacc[nt][r]; \
        const float qk2 = (r < 2) ? qk2lo[nt][r] : qk2hi[nt][r - 2]; \
        const float w2 = fmaf(-d, d, qk2); \
        sc[nt][r] = __builtin_amdgcn_exp2f(__builtin_amdgcn_sqrtf(fabsf(w2))); } \
    frag pa0; \
    pa0.w[0] = cvtpk(sc[0][0], sc[0][1]); pa0.w[1] = cvtpk(sc[0][2], sc[0][3]); \
    pa0.w[2] = cvtpk(sc[1][0], sc[1][1]); pa0.w[3] = cvtpk(sc[1][2], sc[1][3]); \
    __builtin_amdgcn_s_setprio(1); \
    _Pragma("unroll") for (int dt = 0; dt < 4; ++dt) \
      oacc[dt] = __builtin_amdgcn_mfma_f32_16x16x32_bf16(pa0.v, vb0[dt], oacc[dt], 0, 0, 0); \
    lacc = __builtin_amdgcn_mfma_f32_16x16x32_bf16(pa0.v, vone.v, lacc, 0, 0, 0); \
    __builtin_amdgcn_s_setprio(0); \
    _Pragma("unroll") for (int nt = 2; nt < 4; ++nt) \
      _Pragma("unroll") for (int r = 0; r < 4; ++r) { \
        const float d = dacc[nt][r]; \
        const float qk2 = (r < 2) ? qk2lo[nt][r] : qk2hi[nt][r - 2]; \
        const float w2 = fmaf(-d, d, qk2); \
        sc[nt][r] = __builtin_amdgcn_exp2f(__builtin_amdgcn_sqrtf(fabsf(w2))); } \
    frag pa1; \
    pa1.w[0] = cvtpk(sc[2][0], sc[2][1]); pa1.w[1] = cvtpk(sc[2][2], sc[2][3]); \
    pa1.w[2] = cvtpk(sc[3][0], sc[3][1]); pa1.w[3] = cvtpk(sc[3][2], sc[3][3]); \
    __builtin_amdgcn_s_setprio(1); \
    _Pragma("unroll") for (int dt = 0; dt < 4; ++dt) \
      oacc[dt] = __builtin_amdgcn_mfma_f32_16x16x32_bf16(pa1.v, vb1[dt], oacc[dt], 0, 0, 0); \
    lacc = __builtin_amdgcn_mfma_f32_16x16x32_bf16(pa1.v, vone.v, lacc, 0, 0, 0); \
    __builtin_amdgcn_s_setprio(0); \
  } while (0)

  // prologue: stage tile 0 into buffer 0
  STAGE(sd0);
  __syncthreads();

  // 16 x 2-tile unrolled main loop; buffer offsets are compile-time constants.
  // Final iteration's second STAGE reads one tile past the end — lands in
  // adjacent allocated ws regions and is never consumed.
#pragma unroll 1
  for (int it = 0; it < NKT / 2; ++it) {
    STAGE(sd1);                 // tile 2it+1 -> buffer 1
    BODY(0, 0);                 // compute tile 2it from buffer 0
    __syncthreads();
    STAGE(sd0);                 // tile 2it+2 -> buffer 0
    BODY(LBUF, 64);             // compute tile 2it+1 from buffer 1
    __syncthreads();
    kn2p += 128;
  }
#undef STAGE
#undef BODY

  // ---- epilogue: lacc[r] = lsum for q-row 4gg+r (all 16 cols identical) ----
#pragma unroll
  for (int r = 0; r < 4; ++r) {
    const int l = l0 + wv * 16 + gg * 4 + r;
    const float inv = 1.f / lacc[r];
    float* op = Og + (((size_t)b * kL + l) * kH + h) * 64;
#pragma unroll
    for (int dt = 0; dt < 4; ++dt)
      op[dt * 16 + cl] = oacc[dt][r] * inv;
  }
}

extern "C" void kernel_launch(void* const* d_in, const int* in_sizes, int n_in,
                              void* d_out, int out_size, void* d_ws, size_t ws_size,
                              hipStream_t stream) {
  const float* Qg = (const float*)d_in[0];
  const float* Kg = (const float*)d_in[1];
  const float* Vg = (const float*)d_in[2];
  float* Og = (float*)d_out;
  // ws: Kb tiled 8MB | Vt tiled 8MB | kn2 f32 256KB  -> 16.25MB total
  char* Kb = (char*)d_ws;
  char* Vt = (char*)d_ws + ((size_t)8 << 20);
  float* kn2g = (float*)((char*)d_ws + ((size_t)16 << 20));
  prep_k<<<2048, 256, 0, stream>>>(Kg, Kb, kn2g);
  prep_v<<<1024, 256, 0, stream>>>(Vg, Vt);
  geo_attn_kernel<<<dim3(1024), dim3(256), 0, stream>>>(Qg, Kb, Vt, kn2g, Og);
}

// Round 10
// 71.421 us; speedup vs baseline: 1.0053x; 1.0053x over previous
//
#include <hip/hip_runtime.h>

typedef __attribute__((ext_vector_type(2))) float f32x2;
typedef __attribute__((ext_vector_type(4))) float f32x4;
typedef __attribute__((ext_vector_type(4))) float float4v;
typedef __attribute__((ext_vector_type(8))) short bf16x8;
typedef __attribute__((ext_vector_type(8))) unsigned short ushort8;

#define DEVI static __device__ __forceinline__

namespace {
constexpr int kL = 2048, kS = 2048, kH = 8;
constexpr int QB = 128, NKT = 32;
constexpr float kC = 0.18033688f;        // (1/8) * log2(e), folded into Q
constexpr int TILE = 8192;               // bytes per K or V tile
constexpr int BH = 32 * TILE;            // bytes per (b,h) per tensor
constexpr int LBUF = 2 * TILE;           // 16384 B per LDS buffer (K|V)
}

// XOR swizzle on flat byte offset for [rows][64] bf16 tiles (128B row stride).
DEVI int swz(int byteoff) { return byteoff ^ (((byteoff >> 7) & 7) << 4); }

DEVI unsigned cvtpk(float lo, float hi) {
  unsigned r;
  asm("v_cvt_pk_bf16_f32 %0, %1, %2" : "=v"(r) : "v"(lo), "v"(hi));
  return r;
}

DEVI f32x2 pkmul(f32x2 a, f32x2 b) {
  f32x2 r;
  asm("v_pk_mul_f32 %0, %1, %2" : "=v"(r) : "v"(a), "v"(b));
  return r;
}

// ---------- prepass 1: K -> tiled, PRE-SWIZZLED bf16 tiles; kn2 separate ----------
__global__ __launch_bounds__(256) void prep_k(const float* __restrict__ Kg,
                                              char* __restrict__ Kb,
                                              float* __restrict__ kn2g) {
  const int chunk = (int)blockIdx.x * 256 + (int)threadIdx.x;  // one 16B chunk
  const int tile = chunk >> 9;
  const int i = chunk & 511;
  const int bh = tile >> 5, kt = tile & 31;
  const int b = bh >> 3, h = bh & 7;
  const int row = i >> 3;
  const int colsel = (i & 7) ^ (row & 7);     // swz on chunk index
  const int s = kt * 64 + row;
  const float* src = Kg + (((size_t)b * kS + s) * kH + h) * 64 + colsel * 8;
  float4v v0 = *(const float4v*)(src);
  float4v v1 = *(const float4v*)(src + 4);
  float pn = v0.x*v0.x + v0.y*v0.y + v0.z*v0.z + v0.w*v0.w
           + v1.x*v1.x + v1.y*v1.y + v1.z*v1.z + v1.w*v1.w;
  union { unsigned w[4]; ushort8 u; } o;
  o.w[0] = cvtpk(v0.x, v0.y); o.w[1] = cvtpk(v0.z, v0.w);
  o.w[2] = cvtpk(v1.x, v1.y); o.w[3] = cvtpk(v1.z, v1.w);
  *(ushort8*)(Kb + (size_t)tile * TILE + i * 16) = o.u;
  pn += __shfl_xor(pn, 1);
  pn += __shfl_xor(pn, 2);
  pn += __shfl_xor(pn, 4);
  if ((i & 7) == 0) kn2g[tile * 64 + row] = pn;  // exact f32 |k|^2
}

// ---------- prepass 2: V -> tiled, sigma-permuted, PRE-SWIZZLED bf16 ----------
__global__ __launch_bounds__(256) void prep_v(const float* __restrict__ Vg,
                                              char* __restrict__ Vt) {
  __shared__ char tile[64 * 128];  // [s][d] bf16, swizzled
  const int t = (int)threadIdx.x;
  const int bid = (int)blockIdx.x;
  const int st = bid & 31, bh = bid >> 5;
  const int b = bh >> 3, h = bh & 7;
  {
    const int sl = t >> 2, c0 = (t & 3) * 16;
    const float* src = Vg + (((size_t)b * kS + st * 64 + sl) * kH + h) * 64 + c0;
    float4v v0 = *(const float4v*)(src);
    float4v v1 = *(const float4v*)(src + 4);
    float4v v2 = *(const float4v*)(src + 8);
    float4v v3 = *(const float4v*)(src + 12);
    union { unsigned w[4]; ushort8 u; } t0, t1;
    t0.w[0] = cvtpk(v0.x, v0.y); t0.w[1] = cvtpk(v0.z, v0.w);
    t0.w[2] = cvtpk(v1.x, v1.y); t0.w[3] = cvtpk(v1.z, v1.w);
    t1.w[0] = cvtpk(v2.x, v2.y); t1.w[1] = cvtpk(v2.z, v2.w);
    t1.w[2] = cvtpk(v3.x, v3.y); t1.w[3] = cvtpk(v3.z, v3.w);
    *(ushort8*)(tile + swz(sl * 128 + c0 * 2)) = t0.u;
    *(ushort8*)(tile + swz(sl * 128 + c0 * 2 + 16)) = t1.u;
  }
  __syncthreads();
  char* dst = Vt + (size_t)bid * TILE;
#pragma unroll
  for (int cc = 0; cc < 2; ++cc) {
    const int i = t * 2 + cc;
    const int z = swz(i * 16);
    const int d = z >> 7;
    const int k0 = ((z >> 4) & 7) * 8;
    union { unsigned short s[8]; ushort8 u; } o;
#pragma unroll
    for (int j = 0; j < 8; ++j) {
      const int k = k0 + j;
      const int sig = (((k >> 5) * 2 + ((k & 7) >> 2)) << 4) |
                      (((k >> 3) & 3) << 2) | (k & 3);
      o.s[j] = *(const unsigned short*)(tile + swz(sig * 128 + d * 2));
    }
    *(ushort8*)(dst + i * 16) = o.u;
  }
}

// ---------- main attention kernel: 4 waves x 32 q-rows (QB=128) ----------
// Each wave runs the proven round-8 tile body TWICE (q-halves A then B),
// sequentially, sharing the V-fragment LDS reads. Only one dacc/qk2 set live
// at a time (low register pressure).
__global__ __launch_bounds__(256, 2) void geo_attn_kernel(
    const float* __restrict__ Qg, const char* __restrict__ Kb,
    const char* __restrict__ Vt, const float* __restrict__ kn2g,
    float* __restrict__ Og) {
  // two buffers, each: 8192 B K tile | 8192 B V tile (32 KiB total)
  __shared__ char lds[2 * LBUF];

  const int t = (int)threadIdx.x;
  const int wv = t >> 6, lane = t & 63, gg = lane >> 4, cl = lane & 15;
  // XCD-aware decode: n&7 = XCD (round-robin dispatch); each XCD gets 4 bh
  // (2MB K+V working set < 4MB XCD L2) x 16 q-blocks.
  const int n = (int)blockIdx.x;
  const int bh = (n & 7) * 4 + ((n >> 3) & 3);
  const int l0 = (n >> 5) * QB;
  const int b = bh >> 3, h = bh & 7;

  union frag { bf16x8 v; unsigned w[4]; };

  // ---- Q fragments for rows qA = l0+wv*32+cl and qB = qA+16, scaled by kC ----
  const int qA = l0 + wv * 32 + cl;
  const float* qpA = Qg + (((size_t)b * kL + qA) * kH + h) * 64;
  const float* qpB = qpA + 16 * kH * 64;
  frag qbA0, qbA1, qbB0, qbB1;
  f32x2 qn2dA, qn2dB;
  {
    float4v x0 = *(const float4v*)(qpA + gg * 8);
    float4v x1 = *(const float4v*)(qpA + gg * 8 + 4);
    float4v x2 = *(const float4v*)(qpA + gg * 8 + 32);
    float4v x3 = *(const float4v*)(qpA + gg * 8 + 36);
    x0 *= kC; x1 *= kC; x2 *= kC; x3 *= kC;
    float pn = 0.f;
#pragma unroll
    for (int j = 0; j < 4; ++j) {
      pn = fmaf(x0[j], x0[j], pn); pn = fmaf(x1[j], x1[j], pn);
      pn = fmaf(x2[j], x2[j], pn); pn = fmaf(x3[j], x3[j], pn);
    }
    qbA0.w[0] = cvtpk(x0.x, x0.y); qbA0.w[1] = cvtpk(x0.z, x0.w);
    qbA0.w[2] = cvtpk(x1.x, x1.y); qbA0.w[3] = cvtpk(x1.z, x1.w);
    qbA1.w[0] = cvtpk(x2.x, x2.y); qbA1.w[1] = cvtpk(x2.z, x2.w);
    qbA1.w[2] = cvtpk(x3.x, x3.y); qbA1.w[3] = cvtpk(x3.z, x3.w);
    pn += __shfl_xor(pn, 16);
    pn += __shfl_xor(pn, 32);
    qn2dA = (f32x2){pn, pn};
  }
  {
    float4v x0 = *(const float4v*)(qpB + gg * 8);
    float4v x1 = *(const float4v*)(qpB + gg * 8 + 4);
    float4v x2 = *(const float4v*)(qpB + gg * 8 + 32);
    float4v x3 = *(const float4v*)(qpB + gg * 8 + 36);
    x0 *= kC; x1 *= kC; x2 *= kC; x3 *= kC;
    float pn = 0.f;
#pragma unroll
    for (int j = 0; j < 4; ++j) {
      pn = fmaf(x0[j], x0[j], pn); pn = fmaf(x1[j], x1[j], pn);
      pn = fmaf(x2[j], x2[j], pn); pn = fmaf(x3[j], x3[j], pn);
    }
    qbB0.w[0] = cvtpk(x0.x, x0.y); qbB0.w[1] = cvtpk(x0.z, x0.w);
    qbB0.w[2] = cvtpk(x1.x, x1.y); qbB0.w[3] = cvtpk(x1.z, x1.w);
    qbB1.w[0] = cvtpk(x2.x, x2.y); qbB1.w[1] = cvtpk(x2.z, x2.w);
    qbB1.w[2] = cvtpk(x3.x, x3.y); qbB1.w[3] = cvtpk(x3.z, x3.w);
    pn += __shfl_xor(pn, 16);
    pn += __shfl_xor(pn, 32);
    qn2dB = (f32x2){pn, pn};
  }

  frag vone;  // all-ones bf16 B-fragment for P row-sums on the MFMA pipe
  vone.w[0] = vone.w[1] = vone.w[2] = vone.w[3] = 0x3F803F80u;

  // ---- per-lane LDS read bases; all reads are base + compile-time offset ----
  const char* pA = lds + ((cl * 128 + gg * 16) ^ ((cl & 7) << 4));
  const char* pB = lds + ((cl * 128 + gg * 16 + 64) ^ ((cl & 7) << 4));

  // ---- staging: waves 0-1 own the K tile (4KB each), waves 2-3 the V tile ----
  const bool isK = (wv < 2);
  const char* gp = (isK ? Kb : Vt) + (size_t)bh * BH + (wv & 1) * 4096 + lane * 16;
  const int ldsoff = (isK ? 0 : TILE) + (wv & 1) * 4096;
  char* const sd0 = lds + ldsoff;          // stage dest, buffer 0
  char* const sd1 = lds + LBUF + ldsoff;   // stage dest, buffer 1
  const float* kn2p = kn2g + bh * 2048 + gg * 4;

#define STAGE(SD) do { \
    __builtin_amdgcn_global_load_lds((__attribute__((address_space(1))) void*)(gp),        (__attribute__((address_space(3))) void*)(SD),        16, 0, 0); \
    __builtin_amdgcn_global_load_lds((__attribute__((address_space(1))) void*)(gp + 1024), (__attribute__((address_space(3))) void*)((SD) + 1024), 16, 0, 0); \
    __builtin_amdgcn_global_load_lds((__attribute__((address_space(1))) void*)(gp + 2048), (__attribute__((address_space(3))) void*)((SD) + 2048), 16, 0, 0); \
    __builtin_amdgcn_global_load_lds((__attribute__((address_space(1))) void*)(gp + 3072), (__attribute__((address_space(3))) void*)((SD) + 3072), 16, 0, 0); \
    gp += TILE; \
  } while (0)

  f32x4 oaccA[4], oaccB[4];
#pragma unroll
  for (int dt = 0; dt < 4; ++dt) {
    oaccA[dt] = (f32x4){0.f, 0.f, 0.f, 0.f};
    oaccB[dt] = (f32x4){0.f, 0.f, 0.f, 0.f};
  }
  f32x4 laccA = (f32x4){0.f, 0.f, 0.f, 0.f};
  f32x4 laccB = (f32x4){0.f, 0.f, 0.f, 0.f};

  // One q-half tile body (round-8 proven structure). Uses outer vb0/vb1/kn2v.
#define HBODY(BO, Q0, Q1, QN2D, OACC, LACC) do { \
    f32x4 dacc[4]; \
    __builtin_amdgcn_s_setprio(1); \
    _Pragma("unroll") for (int nt = 0; nt < 4; ++nt) { \
      bf16x8 ka0 = *(const bf16x8*)(pA + (BO) + nt * 2048); \
      bf16x8 ka1 = *(const bf16x8*)(pB + (BO) + nt * 2048); \
      f32x4 acc = {0.f, 0.f, 0.f, 0.f}; \
      acc = __builtin_amdgcn_mfma_f32_16x16x32_bf16(ka0, (Q0).v, acc, 0, 0, 0); \
      dacc[nt] = __builtin_amdgcn_mfma_f32_16x16x32_bf16(ka1, (Q1).v, acc, 0, 0, 0); } \
    __builtin_amdgcn_s_setprio(0); \
    f32x2 qk2lo[4], qk2hi[4]; \
    _Pragma("unroll") for (int nt = 0; nt < 4; ++nt) { \
      const f32x2 klo = {kn2v[nt][0], kn2v[nt][1]}; \
      const f32x2 khi = {kn2v[nt][2], kn2v[nt][3]}; \
      qk2lo[nt] = pkmul(QN2D, klo); \
      qk2hi[nt] = pkmul(QN2D, khi); } \
    float sc[4][4]; \
    _Pragma("unroll") for (int nt = 0; nt < 2; ++nt) \
      _Pragma("unroll") for (int r = 0; r < 4; ++r) { \
        const float d = dacc[nt][r]; \
        const float qk2 = (r < 2) ? qk2lo[nt][r] : qk2hi[nt][r - 2]; \
        const float w2 = fmaf(-d, d, qk2); \
        sc[nt][r] = __builtin_amdgcn_exp2f(__builtin_amdgcn_sqrtf(fabsf(w2))); } \
    frag pa0; \
    pa0.w[0] = cvtpk(sc[0][0], sc[0][1]); pa0.w[1] = cvtpk(sc[0][2], sc[0][3]); \
    pa0.w[2] = cvtpk(sc[1][0], sc[1][1]); pa0.w[3] = cvtpk(sc[1][2], sc[1][3]); \
    __builtin_amdgcn_s_setprio(1); \
    _Pragma("unroll") for (int dt = 0; dt < 4; ++dt) \
      OACC[dt] = __builtin_amdgcn_mfma_f32_16x16x32_bf16(pa0.v, vb0[dt], OACC[dt], 0, 0, 0); \
    LACC = __builtin_amdgcn_mfma_f32_16x16x32_bf16(pa0.v, vone.v, LACC, 0, 0, 0); \
    __builtin_amdgcn_s_setprio(0); \
    _Pragma("unroll") for (int nt = 2; nt < 4; ++nt) \
      _Pragma("unroll") for (int r = 0; r < 4; ++r) { \
        const float d = dacc[nt][r]; \
        const float qk2 = (r < 2) ? qk2lo[nt][r] : qk2hi[nt][r - 2]; \
        const float w2 = fmaf(-d, d, qk2); \
        sc[nt][r] = __builtin_amdgcn_exp2f(__builtin_amdgcn_sqrtf(fabsf(w2))); } \
    frag pa1; \
    pa1.w[0] = cvtpk(sc[2][0], sc[2][1]); pa1.w[1] = cvtpk(sc[2][2], sc[2][3]); \
    pa1.w[2] = cvtpk(sc[3][0], sc[3][1]); pa1.w[3] = cvtpk(sc[3][2], sc[3][3]); \
    __builtin_amdgcn_s_setprio(1); \
    _Pragma("unroll") for (int dt = 0; dt < 4; ++dt) \
      OACC[dt] = __builtin_amdgcn_mfma_f32_16x16x32_bf16(pa1.v, vb1[dt], OACC[dt], 0, 0, 0); \
    LACC = __builtin_amdgcn_mfma_f32_16x16x32_bf16(pa1.v, vone.v, LACC, 0, 0, 0); \
    __builtin_amdgcn_s_setprio(0); \
  } while (0)

  // Full tile: shared kn2 + V fragments, then both q-halves sequentially.
#define BODY(BO, KF) do { \
    float4v kn2v[4]; \
    _Pragma("unroll") for (int nt = 0; nt < 4; ++nt) \
      kn2v[nt] = *(const float4v*)(kn2p + (KF) + nt * 16); \
    bf16x8 vb0[4], vb1[4]; \
    _Pragma("unroll") for (int dt = 0; dt < 4; ++dt) { \
      vb0[dt] = *(const bf16x8*)(pA + (BO) + TILE + dt * 2048); \
      vb1[dt] = *(const bf16x8*)(pB + (BO) + TILE + dt * 2048); } \
    HBODY(BO, qbA0, qbA1, qn2dA, oaccA, laccA); \
    HBODY(BO, qbB0, qbB1, qn2dB, oaccB, laccB); \
  } while (0)

  // prologue: stage tile 0 into buffer 0
  STAGE(sd0);
  __syncthreads();

  // 16 x 2-tile unrolled main loop; buffer offsets are compile-time constants.
  // Final iteration's second STAGE reads one tile past the end — lands in
  // adjacent allocated ws regions and is never consumed.
#pragma unroll 1
  for (int it = 0; it < NKT / 2; ++it) {
    STAGE(sd1);                 // tile 2it+1 -> buffer 1
    BODY(0, 0);                 // compute tile 2it from buffer 0
    __syncthreads();
    STAGE(sd0);                 // tile 2it+2 -> buffer 0
    BODY(LBUF, 64);             // compute tile 2it+1 from buffer 1
    __syncthreads();
    kn2p += 128;
  }
#undef STAGE
#undef BODY
#undef HBODY

  // ---- epilogue: lacc[r] = lsum for q-row 4gg+r (all 16 cols identical) ----
#pragma unroll
  for (int r = 0; r < 4; ++r) {
    const int lA = l0 + wv * 32 + gg * 4 + r;
    const float invA = 1.f / laccA[r];
    float* opA = Og + (((size_t)b * kL + lA) * kH + h) * 64;
#pragma unroll
    for (int dt = 0; dt < 4; ++dt)
      opA[dt * 16 + cl] = oaccA[dt][r] * invA;
    const float invB = 1.f / laccB[r];
    float* opB = opA + 16 * kH * 64;
#pragma unroll
    for (int dt = 0; dt < 4; ++dt)
      opB[dt * 16 + cl] = oaccB[dt][r] * invB;
  }
}

extern "C" void kernel_launch(void* const* d_in, const int* in_sizes, int n_in,
                              void* d_out, int out_size, void* d_ws, size_t ws_size,
                              hipStream_t stream) {
  const float* Qg = (const float*)d_in[0];
  const float* Kg = (const float*)d_in[1];
  const float* Vg = (const float*)d_in[2];
  float* Og = (float*)d_out;
  // ws: Kb tiled 8MB | Vt tiled 8MB | kn2 f32 256KB  -> 16.25MB total
  char* Kb = (char*)d_ws;
  char* Vt = (char*)d_ws + ((size_t)8 << 20);
  float* kn2g = (float*)((char*)d_ws + ((size_t)16 << 20));
  prep_k<<<2048, 256, 0, stream>>>(Kg, Kb, kn2g);
  prep_v<<<1024, 256, 0, stream>>>(Vg, Vt);
  geo_attn_kernel<<<dim3(512), dim3(256), 0, stream>>>(Qg, Kb, Vt, kn2g, Og);
}